// Round 10
// baseline (393.309 us; speedup 1.0000x reference)
//
#include <hip/hip_runtime.h>

#define C_IN  32
#define C_OUT 64
#define KK    27

using frag_ab = __attribute__((ext_vector_type(8))) short;  // 8 bf16
using frag_cd = __attribute__((ext_vector_type(4))) float;  // 4 fp32
using u32x4   = __attribute__((ext_vector_type(4))) unsigned int;  // nt-able

static __device__ inline unsigned short f2bf(float f) {   // RTNE f32->bf16
    unsigned u = __float_as_uint(f);
    return (unsigned short)((u + 0x7fffu + ((u >> 16) & 1u)) >> 16);
}
static __device__ inline unsigned pack2(float a, float b) {
    return (unsigned)f2bf(a) | ((unsigned)f2bf(b) << 16);
}
static __device__ inline float bflo(unsigned u) { return __uint_as_float(u << 16); }
static __device__ inline float bfhi(unsigned u) { return __uint_as_float(u & 0xffff0000u); }

// ===========================================================================
// Fallback path (round-1, passing) if workspace too small
// ===========================================================================
__global__ __launch_bounds__(256) void sic_init_bias(float4* __restrict__ out4,
                                                     const float4* __restrict__ bias4,
                                                     int total4) {
    int idx = blockIdx.x * 256 + threadIdx.x, stride = gridDim.x * 256;
    for (int i = idx; i < total4; i += stride) out4[i] = bias4[i & 15];
}

__global__ __launch_bounds__(256) void sic_scatter(
    const float* __restrict__ feats, const float* __restrict__ weight,
    const int* __restrict__ bwd, const int* __restrict__ in_idx,
    const int* __restrict__ out_idx, float* __restrict__ out, int n_in)
{
    const int k = blockIdx.y, lane = threadIdx.x & 63, wid = threadIdx.x >> 6;
    float w[C_IN];
    const float* wk = weight + k * (C_IN * C_OUT);
#pragma unroll
    for (int i = 0; i < C_IN; ++i) w[i] = wk[i * C_OUT + lane];
    const int waves_total = gridDim.x * 4;
    const long long base = (long long)k * n_in;
    for (int p = blockIdx.x * 4 + wid; p < n_in; p += waves_total) {
        int src = __builtin_amdgcn_readfirstlane(in_idx[base + p]);
        int dst = __builtin_amdgcn_readfirstlane(out_idx[base + p]);
        int row = __builtin_amdgcn_readfirstlane(bwd[src]);
        const float* f = feats + (long long)row * C_IN;
        float acc = 0.0f;
#pragma unroll
        for (int i = 0; i < C_IN; ++i) acc = fmaf(f[i], w[i], acc);
        atomicAdd(out + (long long)dst * C_OUT + lane, acc);
    }
}

// ===========================================================================
// Prep kernels
// ===========================================================================
__global__ __launch_bounds__(512) void sic_zero(int* __restrict__ p, int n) {
    int i = blockIdx.x * 512 + threadIdx.x, stride = gridDim.x * 512;
    for (; i < n; i += stride) p[i] = 0;
}

// feats (f32) -> featsbf (bf16), plus one zeroed pad row at index n_in
__global__ __launch_bounds__(256) void sic_fconv(const float* __restrict__ feats,
                                                 short* __restrict__ featsbf, int n_in) {
    int t = blockIdx.x * 256 + threadIdx.x;
    if (t >= (n_in + 1) * 4) return;
    int row = t >> 2, c8 = (t & 3) * 8;
    uint4 v = {0u, 0u, 0u, 0u};
    if (row < n_in) {
        const float* fp = feats + (size_t)row * C_IN + c8;
        float4 f0 = ((const float4*)fp)[0];
        float4 f1 = ((const float4*)fp)[1];
        v.x = pack2(f0.x, f0.y);
        v.y = pack2(f0.z, f0.w);
        v.z = pack2(f1.x, f1.y);
        v.w = pack2(f1.z, f1.w);
    }
    ((uint4*)featsbf)[t] = v;
}

// weight (f32 [27][32][64]) -> bf16 fragments [27][4][64 lanes][8]
// lane l (g=l>>4, cl=l&15), block nb: elems W[k][g*8+j][nb*16+cl]
__global__ __launch_bounds__(256) void sic_wconv(const float* __restrict__ weight,
                                                 short* __restrict__ wfrag) {
    int t = blockIdx.x * 256 + threadIdx.x;
    if (t >= KK * 4 * 64) return;
    int l = t & 63, nb = (t >> 6) & 3, k = t >> 8;
    int g = l >> 4, cl = l & 15;
    const float* wp = weight + (size_t)k * (C_IN * C_OUT) + nb * 16 + cl;
    float r[8];
#pragma unroll
    for (int j = 0; j < 8; ++j) r[j] = wp[(size_t)(g * 8 + j) * C_OUT];
    uint4 v = {pack2(r[0], r[1]), pack2(r[2], r[3]), pack2(r[4], r[5]), pack2(r[6], r[7])};
    ((uint4*)wfrag)[t] = v;
}

// histogram by destination + per-record ordinal (the atomic's return value)
__global__ __launch_bounds__(256) void sic_hist3(const int* __restrict__ out_idx_seg,
                                                 int* __restrict__ count,
                                                 int* __restrict__ ord, int pseg) {
    int i = blockIdx.x * 256 + threadIdx.x;
    if (i < pseg) {
        ord[i] = atomicAdd(&count[out_idx_seg[i]], 1);  // coalesced ord write
    }
}

// ---- wide 2-level exclusive scan (2048 elems/block) ----
__global__ __launch_bounds__(512) void sic_scanA(const int* __restrict__ in,
                                                 int* __restrict__ outExcl,
                                                 int* __restrict__ sums, int n) {
    __shared__ int sm[512];
    int tid = threadIdx.x;
    int base = blockIdx.x * 2048 + tid * 4;
    int e0 = (base + 0 < n) ? in[base + 0] : 0;
    int e1 = (base + 1 < n) ? in[base + 1] : 0;
    int e2 = (base + 2 < n) ? in[base + 2] : 0;
    int e3 = (base + 3 < n) ? in[base + 3] : 0;
    int s = e0 + e1 + e2 + e3;
    sm[tid] = s;
    __syncthreads();
    for (int off = 1; off < 512; off <<= 1) {
        int t = (tid >= off) ? sm[tid - off] : 0;
        __syncthreads();
        sm[tid] += t;
        __syncthreads();
    }
    int pre = sm[tid] - s;                   // exclusive within block
    if (base + 0 < n) outExcl[base + 0] = pre;
    if (base + 1 < n) outExcl[base + 1] = pre + e0;
    if (base + 2 < n) outExcl[base + 2] = pre + e0 + e1;
    if (base + 3 < n) outExcl[base + 3] = pre + e0 + e1 + e2;
    if (tid == 511) sums[blockIdx.x] = sm[511];
}

__global__ __launch_bounds__(512) void sic_scan_small(int* __restrict__ buf, int n) {
    __shared__ int sm[512];
    int tid = threadIdx.x;
    int e = (tid < n) ? buf[tid] : 0;
    sm[tid] = e;
    __syncthreads();
    for (int off = 1; off < 512; off <<= 1) {
        int t = (tid >= off) ? sm[tid - off] : 0;
        __syncthreads();
        sm[tid] += t;
        __syncthreads();
    }
    if (tid < n) buf[tid] = sm[tid] - e;
}

__global__ __launch_bounds__(512) void sic_addbackA(int* __restrict__ arr,
                                                    const int* __restrict__ sums, int n) {
    int s = sums[blockIdx.x];
    int base = blockIdx.x * 2048 + threadIdx.x * 4;
#pragma unroll
    for (int i = 0; i < 4; ++i)
        if (base + i < n) arr[base + i] += s;
}

// ===========================================================================
// Phase A: per-k MFMA; slot = startv[dst] + ord[rec]; DIRECT register store.
// All 4 lanes (g=0..3) of record cl share idx/pos (idx depends only on cl).
// Lane (g,cl) stores d0..d3 as 2x16B at row(pos) + g*32B. Row layout is a
// fixed permutation: uint m = g*8 + nb*2 + jj holds channels
// nb*16 + g*4 + 2*jj {+0,+1}. Reduce unpermutes via its output address map.
// ===========================================================================
__global__ __launch_bounds__(256) void sic_gemm4(
    const int* __restrict__ in_idx,     // global rulebook [KK][n_in]
    const int* __restrict__ out_idx,
    const int* __restrict__ bwd,
    const int* __restrict__ ord,        // segment-local [kseg*n_in]
    const int* __restrict__ startv,     // per-dst slot base
    const short* __restrict__ featsbf,  // [(n_in+pad)][32] bf16
    const short* __restrict__ wfrag,    // [KK][4][64][8] bf16
    unsigned int* __restrict__ contribU,// row r at contribU[r*32]
    int n_in, int k0, int zrow)
{
    const int kk   = k0 + blockIdx.y;
    const int lane = threadIdx.x & 63;
    const int wid  = threadIdx.x >> 6;
    const int g = lane >> 4, cl = lane & 15;

    const frag_ab wa0 = *(const frag_ab*)(wfrag + ((size_t)(kk * 4 + 0) * 64 + lane) * 8);
    const frag_ab wa1 = *(const frag_ab*)(wfrag + ((size_t)(kk * 4 + 1) * 64 + lane) * 8);
    const frag_ab wa2 = *(const frag_ab*)(wfrag + ((size_t)(kk * 4 + 2) * 64 + lane) * 8);
    const frag_ab wa3 = *(const frag_ab*)(wfrag + ((size_t)(kk * 4 + 3) * 64 + lane) * 8);
    const frag_cd zf = {0.f, 0.f, 0.f, 0.f};

    const size_t gk  = (size_t)kk * n_in;            // rulebook base (global k)
    const size_t sk  = (size_t)blockIdx.y * n_in;    // ord base (segment-local)
    const int t      = blockIdx.x * 4 + wid;         // one 16-record tile per wave
    const int idx    = t * 16 + cl;                  // same for all g of this cl
    const bool valid = idx < n_in;

    int row = zrow, pos = 0;
    if (valid) {
        row = bwd[in_idx[gk + idx]];                 // fused feats[bwd] gather
        int dst = out_idx[gk + idx];
        pos = startv[dst] + ord[sk + idx];           // slot, no atomics
    }

    frag_ab b = *(const frag_ab*)(featsbf + (size_t)row * C_IN + g * 8);
    frag_cd d0 = __builtin_amdgcn_mfma_f32_16x16x32_bf16(wa0, b, zf, 0, 0, 0);
    frag_cd d1 = __builtin_amdgcn_mfma_f32_16x16x32_bf16(wa1, b, zf, 0, 0, 0);
    frag_cd d2 = __builtin_amdgcn_mfma_f32_16x16x32_bf16(wa2, b, zf, 0, 0, 0);
    frag_cd d3 = __builtin_amdgcn_mfma_f32_16x16x32_bf16(wa3, b, zf, 0, 0, 0);

    if (valid) {
        unsigned int* cp = contribU + (size_t)pos * 32 + g * 8;
        uint4 v0 = {pack2(d0[0], d0[1]), pack2(d0[2], d0[3]),
                    pack2(d1[0], d1[1]), pack2(d1[2], d1[3])};
        uint4 v1 = {pack2(d2[0], d2[1]), pack2(d2[2], d2[3]),
                    pack2(d3[0], d3[1]), pack2(d3[2], d3[3])};
        *(uint4*)(cp)     = v0;    // normal stores: L2 merges the half-lines
        *(uint4*)(cp + 4) = v1;
    }
}

// ===========================================================================
// Phase B: streaming reduce over permuted rows. Thread c8 owns channels
// A = (c8&1)*32 + (c8>>1)*4 + {0..3} and B = A + 16.
// ===========================================================================
__global__ __launch_bounds__(256) void sic_reduce5(
    const unsigned int* __restrict__ contribU,  // row r at contribU[r*32]
    const int* __restrict__ startv, const int* __restrict__ count,
    const float* __restrict__ bias, float* __restrict__ out,
    int n_out, int first)
{
    int t = blockIdx.x * 256 + threadIdx.x;
    int dst = t >> 3, c8 = t & 7;
    if (dst >= n_out) return;
    int s = startv[dst], c = count[dst];

    const int chA = (c8 & 1) * 32 + (c8 >> 1) * 4;
    size_t obA = (size_t)dst * C_OUT + chA;
    size_t obB = obA + 16;
    float4 a0, a1;
    if (first) {
        a0 = *(const float4*)(bias + chA);
        a1 = *(const float4*)(bias + chA + 16);
    } else {
        a0 = *(const float4*)(out + obA);
        a1 = *(const float4*)(out + obB);
    }
    const u32x4* p = (const u32x4*)(contribU + (size_t)s * 32) + c8;
    int j = 0;
    for (; j + 2 <= c; j += 2) {
        u32x4 va = __builtin_nontemporal_load(&p[(size_t)j * 8]);
        u32x4 vb = __builtin_nontemporal_load(&p[(size_t)(j + 1) * 8]);
        a0.x += bflo(va.x); a0.y += bfhi(va.x);
        a0.z += bflo(va.y); a0.w += bfhi(va.y);
        a1.x += bflo(va.z); a1.y += bfhi(va.z);
        a1.z += bflo(va.w); a1.w += bfhi(va.w);
        a0.x += bflo(vb.x); a0.y += bfhi(vb.x);
        a0.z += bflo(vb.y); a0.w += bfhi(vb.y);
        a1.x += bflo(vb.z); a1.y += bfhi(vb.z);
        a1.z += bflo(vb.w); a1.w += bfhi(vb.w);
    }
    if (j < c) {
        u32x4 va = __builtin_nontemporal_load(&p[(size_t)j * 8]);
        a0.x += bflo(va.x); a0.y += bfhi(va.x);
        a0.z += bflo(va.y); a0.w += bfhi(va.y);
        a1.x += bflo(va.z); a1.y += bfhi(va.z);
        a1.z += bflo(va.w); a1.w += bfhi(va.w);
    }
    *(float4*)(out + obA) = a0;
    *(float4*)(out + obB) = a1;
}

// ===========================================================================
extern "C" void kernel_launch(void* const* d_in, const int* in_sizes, int n_in_cnt,
                              void* d_out, int out_size, void* d_ws, size_t ws_size,
                              hipStream_t stream) {
    const float* feats   = (const float*)d_in[0];
    const float* weight  = (const float*)d_in[1];
    const float* bias    = (const float*)d_in[2];
    const int*   bwd     = (const int*)d_in[3];
    const int*   in_idx  = (const int*)d_in[4];
    const int*   out_idx = (const int*)d_in[5];
    float*       out     = (float*)d_out;

    const int n_in  = in_sizes[0] / C_IN;      // 100000
    const int n_out = out_size / C_OUT;        // 800000
    const size_t P  = (size_t)KK * n_in;       // 2.7M records

    const int NCHA = (n_out + 2047) / 2048;    // 391 scan chunks

    // ---- workspace layout (int units) ----
    const size_t NOUTr   = ((size_t)n_out + 255) & ~(size_t)255;
    const size_t o_cnt   = 0;
    const size_t o_stv   = NOUTr;
    const size_t o_s1    = 2 * NOUTr;                    // sums (NCHA <= 512)
    const size_t o_ord   = (o_s1 + 512 + 255) & ~(size_t)255;      // ord (P)
    const size_t o_fbf   = (o_ord + P + 255) & ~(size_t)255;
    const size_t fbf_i   = ((size_t)(n_in + 16) * C_IN * 2 + 3) / 4;
    const size_t o_wfr   = (o_fbf + fbf_i + 255) & ~(size_t)255;
    const size_t wfr_i   = (size_t)KK * 4 * 64 * 8 * 2 / 4;
    const size_t o_ctr   = (o_wfr + wfr_i + 255) & ~(size_t)255;   // contrib

    const size_t ws_ints = ws_size / 4;
    size_t cap_recs = (ws_ints > o_ctr) ? (ws_ints - o_ctr) / 32 : 0;  // 128B/rec
    int kseg_max = (int)(cap_recs / (size_t)n_in);
    if (kseg_max > KK) kseg_max = KK;

    if (kseg_max < 1 || NCHA > 512) {
        // fallback: round-1 atomic path
        const int total4 = out_size / 4;
        hipLaunchKernelGGL(sic_init_bias, dim3(2048), dim3(256), 0, stream,
                           (float4*)out, (const float4*)bias, total4);
        hipLaunchKernelGGL(sic_scatter, dim3(160, KK), dim3(256), 0, stream,
                           feats, weight, bwd, in_idx, out_idx, out, n_in);
        return;
    }

    int* ws = (int*)d_ws;
    int* count  = ws + o_cnt;
    int* startv = ws + o_stv;
    int* sums   = ws + o_s1;
    int* ord    = ws + o_ord;
    short* featsbf = (short*)(ws + o_fbf);
    short* wfrag   = (short*)(ws + o_wfr);
    unsigned int* contribU = (unsigned int*)(ws + o_ctr);

    // one-time conversions
    hipLaunchKernelGGL(sic_fconv, dim3(((n_in + 1) * 4 + 255) / 256), dim3(256), 0, stream,
                       feats, featsbf, n_in);
    hipLaunchKernelGGL(sic_wconv, dim3((KK * 4 * 64 + 255) / 256), dim3(256), 0, stream,
                       weight, wfrag);

    const int ntiles  = (n_in + 15) / 16;
    const int gx_gemm = (ntiles + 3) / 4;      // one tile per wave

    // segment loop over k (single pass when contrib fits: kseg_max == 27)
    for (int k0 = 0; k0 < KK; k0 += kseg_max) {
        const int kseg = (KK - k0 < kseg_max) ? (KK - k0) : kseg_max;
        const int pseg = kseg * n_in;
        const int gp   = (pseg + 255) / 256;
        const int* oseg = out_idx + (size_t)k0 * n_in;

        hipLaunchKernelGGL(sic_zero, dim3(1024), dim3(512), 0, stream, count, n_out);
        hipLaunchKernelGGL(sic_hist3, dim3(gp), dim3(256), 0, stream,
                           oseg, count, ord, pseg);
        hipLaunchKernelGGL(sic_scanA, dim3(NCHA), dim3(512), 0, stream,
                           count, startv, sums, n_out);
        hipLaunchKernelGGL(sic_scan_small, dim3(1), dim3(512), 0, stream, sums, NCHA);
        hipLaunchKernelGGL(sic_addbackA, dim3(NCHA), dim3(512), 0, stream,
                           startv, sums, n_out);
        // MFMA + dst-sorted direct-register 128B-row scatter (atomic/LDS-free)
        hipLaunchKernelGGL(sic_gemm4, dim3(gx_gemm, kseg), dim3(256), 0, stream,
                           in_idx, out_idx, bwd, ord, startv,
                           featsbf, wfrag, contribU, n_in, k0, n_in);
        // streaming reduce: 8 threads per output row (permuted-row aware)
        hipLaunchKernelGGL(sic_reduce5, dim3((n_out * 8 + 255) / 256), dim3(256), 0, stream,
                           contribU, startv, count, bias, out,
                           n_out, (k0 == 0) ? 1 : 0);
    }
}